// Round 3
// baseline (6145.911 us; speedup 1.0000x reference)
//
#include <hip/hip_runtime.h>
#include <hip/hip_bf16.h>

#define BB 256      // batch
#define CC 2048     // code_num
#define HD 1024     // hidden
#define TT 64       // max_len
#define H3 3072
#define NBLK 256

typedef __attribute__((ext_vector_type(8))) short bf16x8;
typedef __attribute__((ext_vector_type(4))) float f32x4;

__device__ __forceinline__ float sigmoidf_(float x){ return 1.0f/(1.0f+__expf(-x)); }
__device__ __forceinline__ float tanhf_(float x){ float e=__expf(2.0f*x); return 1.0f - 2.0f/(e+1.0f); }
__device__ __forceinline__ bf16x8 ldfrag(const __hip_bfloat16* p){
  return *reinterpret_cast<const bf16x8*>(p);
}
__device__ __forceinline__ unsigned short bfbits(float x){
  __hip_bfloat16 b = __float2bfloat16(x);
  return *reinterpret_cast<unsigned short*>(&b);
}

__global__ void cvt_f32_bf16(const float* __restrict__ in, __hip_bfloat16* __restrict__ out, int n){
  int i = (blockIdx.x*blockDim.x + threadIdx.x)*4;
  int stride = gridDim.x*blockDim.x*4;
  for (; i < n; i += stride){
    float4 v = *reinterpret_cast<const float4*>(in + i);
    ushort4 s;
    s.x = bfbits(v.x); s.y = bfbits(v.y); s.z = bfbits(v.z); s.w = bfbits(v.w);
    *reinterpret_cast<ushort4*>(out + i) = s;
  }
}

// Device-scope grid barrier. Safe: grid == 256 blocks, each CU can host >=1
// block (VGPR<=128, LDS 51KB), so all blocks are resident simultaneously.
__device__ __forceinline__ void gridbar(unsigned* cnt, unsigned* gen){
  __syncthreads();
  if (threadIdx.x == 0){
    __threadfence();  // release: push this block's writes to coherent point
    unsigned g = __hip_atomic_load(gen, __ATOMIC_RELAXED, __HIP_MEMORY_SCOPE_AGENT);
    unsigned a = __hip_atomic_fetch_add(cnt, 1u, __ATOMIC_ACQ_REL, __HIP_MEMORY_SCOPE_AGENT);
    if (a == NBLK-1u){
      __hip_atomic_store(cnt, 0u, __ATOMIC_RELAXED, __HIP_MEMORY_SCOPE_AGENT);
      __hip_atomic_store(gen, g+1u, __ATOMIC_RELEASE, __HIP_MEMORY_SCOPE_AGENT);
    } else {
      while (__hip_atomic_load(gen, __ATOMIC_RELAXED, __HIP_MEMORY_SCOPE_AGENT) == g){
        __builtin_amdgcn_s_sleep(2);
      }
    }
    __threadfence();  // acquire: invalidate stale cached lines
  }
  __syncthreads();
}

#define MFMA(a,b,c) __builtin_amdgcn_mfma_f32_16x16x32_bf16((a),(b),(c),0,0,0)

// Persistent GRU kernel. 256 blocks x 1024 threads, 1 block/CU pinned for the
// whole sequence. bm = blockIdx>>6 (m-replica), bsub = blockIdx&63 (bj/bc).
// The 4 bm-replicas of a given bsub are blockIdx = bsub + 64*bm, all congruent
// mod 8 -> same XCD -> weight slice (2.8 MB/XCD) stays L2-resident.
__global__ __launch_bounds__(1024, 4) void gru_persistent(
    const __hip_bfloat16* __restrict__ wih,     // [3H][C]
    const __hip_bfloat16* __restrict__ whh,     // [3H][H]
    const __hip_bfloat16* __restrict__ wout,    // [C][H]
    const __hip_bfloat16* __restrict__ noise16, // [B][H]
    const float* __restrict__ bih,
    const float* __restrict__ bhh,
    const float* __restrict__ bout,
    float* __restrict__ samples,                // [B][T][C]
    float* __restrict__ hiddens,                // [B][T][H]
    __hip_bfloat16* codes16,                    // [B][C]
    __hip_bfloat16* h16a, __hip_bfloat16* h16b, // [B][H] ping-pong
    unsigned* bar)
{
  __shared__ float red[8*64*25];   // phase-A reduction; phase B uses a subset

  const int tid  = threadIdx.x;
  const int lane = tid & 63;
  const int wid  = tid >> 6;     // 0..15
  const int ws   = wid & 3;      // m-sub select
  const int kc   = wid >> 2;     // K-chunk select (0..3)
  const int bm   = blockIdx.x >> 6;   // 0..3
  const int bsub = blockIdx.x & 63;   // bj (cell) / bc (logits)
  const int m0   = bm*64 + ws*16;
  const int rl   = lane & 15;
  const int kg   = lane >> 4;
  unsigned* cnt = bar;
  unsigned* gen = bar + 32;

  // hoisted per-thread constants
  const int jA  = bsub*16 + rl;           // cell output column
  const int caB = bsub*32 + rl;           // logits output columns
  const int cbB = caB + 16;
  const float bir = bih[jA], biz = bih[jA+HD], bin = bih[jA+2*HD];
  const float bhr = bhh[jA], bhz = bhh[jA+HD], bhn = bhh[jA+2*HD];
  const float b0 = bout[caB], b1 = bout[cbB];
  const int rbase = m0 + kg*4;

  // ---------------- phase B closure ----------------
  auto phaseB = [&](const __hip_bfloat16* act, int t){
    const __hip_bfloat16* arow = act  + (size_t)(m0+rl)*HD + kc*256 + kg*8;
    const __hip_bfloat16* w0   = wout + (size_t)(bsub*32+rl)*HD + kc*256 + kg*8;
    const __hip_bfloat16* w1   = w0 + (size_t)16*HD;
    f32x4 acc0 = {0.f,0.f,0.f,0.f}, acc1 = {0.f,0.f,0.f,0.f};
#pragma unroll 4
    for (int k = 0; k < 256; k += 32){
      bf16x8 a  = ldfrag(arow + k);
      bf16x8 f0 = ldfrag(w0 + k);
      bf16x8 f1 = ldfrag(w1 + k);
      acc0 = MFMA(a, f0, acc0);
      acc1 = MFMA(a, f1, acc1);
    }
    if (kc >= 1){
      float* p = &red[((kc-1)*4 + ws)*64*9 + lane*9];
#pragma unroll
      for (int q = 0; q < 4; q++){ p[q] = acc0[q]; p[4+q] = acc1[q]; }
    }
    __syncthreads();
    if (kc == 0){
#pragma unroll
      for (int s = 0; s < 3; s++){
        const float* p = &red[(s*4 + ws)*64*9 + lane*9];
#pragma unroll
        for (int q = 0; q < 4; q++){ acc0[q] += p[q]; acc1[q] += p[4+q]; }
      }
#pragma unroll
      for (int q = 0; q < 4; q++){
        const int brow = rbase + q;
        float s0 = sigmoidf_(acc0[q] + b0);
        float s1 = sigmoidf_(acc1[q] + b1);
        samples[(size_t)brow*TT*CC + (size_t)t*CC + caB] = s0;
        samples[(size_t)brow*TT*CC + (size_t)t*CC + cbB] = s1;
        codes16[(size_t)brow*CC + caB] = __float2bfloat16(s0);
        codes16[(size_t)brow*CC + cbB] = __float2bfloat16(s1);
      }
    }
  };

  // ---------------- phase A closure ----------------
  auto phaseA = [&](const __hip_bfloat16* hprev, __hip_bfloat16* hnext,
                    int t, int first){
    const __hip_bfloat16* arow = codes16 + (size_t)(m0+rl)*CC + kc*512 + kg*8;
    const __hip_bfloat16* wr   = wih     + (size_t)(bsub*16+rl)*CC + kc*512 + kg*8;
    const __hip_bfloat16* wz   = wr + (size_t)HD*CC;
    const __hip_bfloat16* wn   = wz + (size_t)HD*CC;
    f32x4 zz4 = {0.f,0.f,0.f,0.f};
    f32x4 a0=zz4, a1=zz4, a2=zz4, a3=zz4, a4=zz4, a5=zz4;
#pragma unroll 4
    for (int k = 0; k < 512; k += 32){
      bf16x8 a  = ldfrag(arow + k);
      bf16x8 fr = ldfrag(wr + k);
      bf16x8 fz = ldfrag(wz + k);
      bf16x8 fn = ldfrag(wn + k);
      a0 = MFMA(a, fr, a0);
      a1 = MFMA(a, fz, a1);
      a2 = MFMA(a, fn, a2);
    }
    if (!first){
      const __hip_bfloat16* hrow = hprev + (size_t)(m0+rl)*HD + kc*256 + kg*8;
      const __hip_bfloat16* vr   = whh   + (size_t)(bsub*16+rl)*HD + kc*256 + kg*8;
      const __hip_bfloat16* vz   = vr + (size_t)HD*HD;
      const __hip_bfloat16* vn   = vz + (size_t)HD*HD;
#pragma unroll 4
      for (int k = 0; k < 256; k += 32){
        bf16x8 a  = ldfrag(hrow + k);
        bf16x8 fr = ldfrag(vr + k);
        bf16x8 fz = ldfrag(vz + k);
        bf16x8 fn = ldfrag(vn + k);
        a3 = MFMA(a, fr, a3);
        a4 = MFMA(a, fz, a4);
        a5 = MFMA(a, fn, a5);
      }
    }
    // two-stage K-chunk reduction through LDS
    if (kc >= 2){
      float* p = &red[((kc-2)*4 + ws)*64*25 + lane*25];
#pragma unroll
      for (int q = 0; q < 4; q++){
        p[q] = a0[q]; p[4+q] = a1[q]; p[8+q] = a2[q];
        p[12+q] = a3[q]; p[16+q] = a4[q]; p[20+q] = a5[q];
      }
    }
    __syncthreads();
    if (kc < 2){
      const float* p = &red[(kc*4 + ws)*64*25 + lane*25];
#pragma unroll
      for (int q = 0; q < 4; q++){
        a0[q] += p[q]; a1[q] += p[4+q]; a2[q] += p[8+q];
        a3[q] += p[12+q]; a4[q] += p[16+q]; a5[q] += p[20+q];
      }
    }
    __syncthreads();
    if (kc == 1){
      float* p = &red[ws*64*25 + lane*25];
#pragma unroll
      for (int q = 0; q < 4; q++){
        p[q] = a0[q]; p[4+q] = a1[q]; p[8+q] = a2[q];
        p[12+q] = a3[q]; p[16+q] = a4[q]; p[20+q] = a5[q];
      }
    }
    __syncthreads();
    if (kc == 0){
      const float* p = &red[ws*64*25 + lane*25];
#pragma unroll
      for (int q = 0; q < 4; q++){
        a0[q] += p[q]; a1[q] += p[4+q]; a2[q] += p[8+q];
        a3[q] += p[12+q]; a4[q] += p[16+q]; a5[q] += p[20+q];
      }
#pragma unroll
      for (int q = 0; q < 4; q++){
        const int brow = rbase + q;
        float ir = a0[q] + bir, iz = a1[q] + biz, inn = a2[q] + bin;
        float hr = a3[q] + bhr, hz = a4[q] + bhz, hn = a5[q] + bhn;
        float r = sigmoidf_(ir + hr);
        float z = sigmoidf_(iz + hz);
        float n = tanhf_(inn + r*hn);
        float hp = first ? 0.0f : __bfloat162float(hprev[(size_t)brow*HD + jA]);
        float hv = (1.0f - z)*n + z*hp;
        hiddens[(size_t)brow*TT*HD + (size_t)t*HD + jA] = hv;
        hnext[(size_t)brow*HD + jA] = __float2bfloat16(hv);
      }
    }
  };

  // ---------------- sequence ----------------
  phaseB(noise16, 0);          // samples[:,0,:], codes16 = codes0
  gridbar(cnt, gen);

#pragma unroll 1
  for (int t = 0; t < TT; t++){
    __hip_bfloat16* hprev = (t & 1) ? h16a : h16b;
    __hip_bfloat16* hnext = (t & 1) ? h16b : h16a;
    phaseA(hprev, hnext, t, (t == 0) ? 1 : 0);
    gridbar(cnt, gen);
    if (t < TT-1){
      phaseB(hnext, t+1);
      gridbar(cnt, gen);
    }
  }
}

extern "C" void kernel_launch(void* const* d_in, const int* in_sizes, int n_in,
                              void* d_out, int out_size, void* d_ws, size_t ws_size,
                              hipStream_t stream) {
  const float* noise = (const float*)d_in[0];
  const float* W_ih  = (const float*)d_in[1];
  const float* b_ih  = (const float*)d_in[2];
  const float* W_hh  = (const float*)d_in[3];
  const float* b_hh  = (const float*)d_in[4];
  const float* W_out = (const float*)d_in[5];
  const float* b_out = (const float*)d_in[6];

  float* samples = (float*)d_out;                       // [B][T][C]
  float* hiddens = samples + (size_t)BB*TT*CC;          // [B][T][H]

  char* w = (char*)d_ws;
  unsigned* bar = (unsigned*)w;                w += 256;
  __hip_bfloat16* wih16 = (__hip_bfloat16*)w;  w += (size_t)H3*CC*2;
  __hip_bfloat16* whh16 = (__hip_bfloat16*)w;  w += (size_t)H3*HD*2;
  __hip_bfloat16* wout16= (__hip_bfloat16*)w;  w += (size_t)CC*HD*2;
  __hip_bfloat16* noise16=(__hip_bfloat16*)w;  w += (size_t)BB*HD*2;
  __hip_bfloat16* codes16=(__hip_bfloat16*)w;  w += (size_t)BB*CC*2;
  __hip_bfloat16* h16a  = (__hip_bfloat16*)w;  w += (size_t)BB*HD*2;
  __hip_bfloat16* h16b  = (__hip_bfloat16*)w;  w += (size_t)BB*HD*2;

  hipMemsetAsync(bar, 0, 256, stream);
  cvt_f32_bf16<<<2048, 256, 0, stream>>>(W_ih,  wih16,  H3*CC);
  cvt_f32_bf16<<<2048, 256, 0, stream>>>(W_hh,  whh16,  H3*HD);
  cvt_f32_bf16<<<1024, 256, 0, stream>>>(W_out, wout16, CC*HD);
  cvt_f32_bf16<<<256,  256, 0, stream>>>(noise, noise16, BB*HD);

  gru_persistent<<<NBLK, 1024, 0, stream>>>(
      wih16, whh16, wout16, noise16, b_ih, b_hh, b_out,
      samples, hiddens, codes16, h16a, h16b, bar);
}

// Round 4
// 4655.073 us; speedup vs baseline: 1.3203x; 1.3203x over previous
//
#include <hip/hip_runtime.h>
#include <hip/hip_bf16.h>

#define BB 256      // batch
#define CC 2048     // code_num
#define HD 1024     // hidden
#define TT 64       // max_len
#define H3 3072
#define NBLK 256
#define NGRP 8      // groups of batch rows
#define GBLK 32     // blocks per group
#define GROWS 32    // batch rows per group

typedef __attribute__((ext_vector_type(8))) short bf16x8;
typedef __attribute__((ext_vector_type(4))) float f32x4;

__device__ __forceinline__ float sigmoidf_(float x){ return 1.0f/(1.0f+__expf(-x)); }
__device__ __forceinline__ float tanhf_(float x){ float e=__expf(2.0f*x); return 1.0f - 2.0f/(e+1.0f); }
__device__ __forceinline__ bf16x8 ldfrag(const __hip_bfloat16* p){
  return *reinterpret_cast<const bf16x8*>(p);
}
// System-coherent (L2-bypassing) 16B activation load as 2x8B relaxed atomics.
__device__ __forceinline__ bf16x8 ldfrag_sys(const __hip_bfloat16* p){
  const unsigned long long* q = (const unsigned long long*)p;
  unsigned long long lo = __hip_atomic_load(q,   __ATOMIC_RELAXED, __HIP_MEMORY_SCOPE_SYSTEM);
  unsigned long long hi = __hip_atomic_load(q+1, __ATOMIC_RELAXED, __HIP_MEMORY_SCOPE_SYSTEM);
  union { unsigned long long u[2]; bf16x8 v; } x;
  x.u[0]=lo; x.u[1]=hi;
  return x.v;
}
__device__ __forceinline__ unsigned short bfbits(float x){
  __hip_bfloat16 b = __float2bfloat16(x);
  return *reinterpret_cast<unsigned short*>(&b);
}
__device__ __forceinline__ void st_sys_bf16(__hip_bfloat16* p, float v){
  __hip_atomic_store((unsigned short*)p, bfbits(v), __ATOMIC_RELAXED, __HIP_MEMORY_SCOPE_SYSTEM);
}
__device__ __forceinline__ float ld_sys_bf16(const __hip_bfloat16* p){
  unsigned short b = __hip_atomic_load((const unsigned short*)p, __ATOMIC_RELAXED, __HIP_MEMORY_SCOPE_SYSTEM);
  union { unsigned short u; __hip_bfloat16 h; } x; x.u = b;
  return __bfloat162float(x.h);
}

__global__ void cvt_f32_bf16(const float* __restrict__ in, __hip_bfloat16* __restrict__ out, int n){
  int i = (blockIdx.x*blockDim.x + threadIdx.x)*4;
  int stride = gridDim.x*blockDim.x*4;
  for (; i < n; i += stride){
    float4 v = *reinterpret_cast<const float4*>(in + i);
    ushort4 s;
    s.x = bfbits(v.x); s.y = bfbits(v.y); s.z = bfbits(v.z); s.w = bfbits(v.w);
    *reinterpret_cast<ushort4*>(out + i) = s;
  }
}

#define MFMA(a,b,c) __builtin_amdgcn_mfma_f32_16x16x32_bf16((a),(b),(c),0,0,0)

// Persistent GRU. 256 blocks x 1024 threads, 1 block/CU. Group g = blockIdx>>5
// owns batch rows [g*32, g*32+32); bsub = blockIdx&31 selects column slice
// (cell: 32 of 1024 cols; logits: 64 of 2048 cols). All inter-block exchange
// is intra-group via system-scope (L2-bypassing) activation I/O + monotonic
// flag barriers -- NO cache-invalidating fences, so weights stay L2-resident.
__global__ __launch_bounds__(1024, 4) void gru_persistent(
    const __hip_bfloat16* __restrict__ wih,     // [3H][C]
    const __hip_bfloat16* __restrict__ whh,     // [3H][H]
    const __hip_bfloat16* __restrict__ wout,    // [C][H]
    const __hip_bfloat16* __restrict__ noise16, // [B][H]
    const float* __restrict__ bih,
    const float* __restrict__ bhh,
    const float* __restrict__ bout,
    float* __restrict__ samples,                // [B][T][C]
    float* __restrict__ hiddens,                // [B][T][H]
    __hip_bfloat16* codesA, __hip_bfloat16* codesB,   // [B][C] ping-pong
    __hip_bfloat16* hA, __hip_bfloat16* hB,           // [B][H] ping-pong
    unsigned* flagA, unsigned* flagB)
{
  __shared__ float red[8*64*25];   // 51.2 KB reduction scratch (both phases)

  const int tid  = threadIdx.x;
  const int lane = tid & 63;
  const int wid  = tid >> 6;      // 0..15
  const int wsub = wid & 3;       // reduction sub-slot = (cs<<1)|ws
  const int ws   = wid & 1;       // row half (16 rows)
  const int cs   = (wid >> 1) & 1;// col half
  const int kc   = wid >> 2;      // K chunk 0..3
  const int g    = blockIdx.x >> 5;
  const int bsub = blockIdx.x & 31;
  const int rl   = lane & 15;
  const int kg   = lane >> 4;
  const int m0   = g*GROWS + ws*16;   // first batch row of this wave
  const int rbase= m0 + kg*4;

  // cell (phase A) output column, logits (phase B) output columns
  const int jA  = bsub*32 + cs*16 + rl;
  const int caB = bsub*64 + cs*32 + rl;
  const int cbB = caB + 16;
  const float bir = bih[jA], biz = bih[jA+HD], bin = bih[jA+2*HD];
  const float bhr = bhh[jA], bhz = bhh[jA+HD], bhn = bhh[jA+2*HD];
  const float b0 = bout[caB], b1 = bout[cbB];

  // ---- group flag barrier helpers (monotonic generations, no reset) ----
  auto signal = [&](unsigned* flags, unsigned gen){
    __syncthreads();   // compiler drains vmcnt(0) before s_barrier -> all
                       // waves' system stores are visible at L3 here
    if (tid == 0)
      __hip_atomic_store(&flags[g*GBLK + bsub], gen, __ATOMIC_RELAXED, __HIP_MEMORY_SCOPE_SYSTEM);
  };
  auto waitf = [&](unsigned* flags, unsigned gen){
    if (tid < GBLK){
      while (__hip_atomic_load(&flags[g*GBLK + tid], __ATOMIC_RELAXED, __HIP_MEMORY_SCOPE_SYSTEM) < gen)
        __builtin_amdgcn_s_sleep(1);
    }
    __syncthreads();   // compiler memory barrier: no load hoisting above poll
  };

  // ---------------- phase B: codes_t = sigmoid(act @ Wout^T + b) ----------
  auto phaseB = [&](const __hip_bfloat16* act, int t, bool sys){
    __hip_bfloat16* cout = (t & 1) ? codesB : codesA;
    const __hip_bfloat16* arow = act  + (size_t)(m0+rl)*HD + kc*256 + kg*8;
    const __hip_bfloat16* w0   = wout + (size_t)caB*HD + kc*256 + kg*8;
    const __hip_bfloat16* w1   = w0 + (size_t)16*HD;
    f32x4 acc0 = {0.f,0.f,0.f,0.f}, acc1 = {0.f,0.f,0.f,0.f};
#pragma unroll 4
    for (int k = 0; k < 256; k += 32){
      bf16x8 a = sys ? ldfrag_sys(arow + k) : ldfrag(arow + k);
      bf16x8 f0 = ldfrag(w0 + k);
      bf16x8 f1 = ldfrag(w1 + k);
      acc0 = MFMA(a, f0, acc0);
      acc1 = MFMA(a, f1, acc1);
    }
    if (kc >= 1){
      float* p = &red[((kc-1)*4 + wsub)*64*9 + lane*9];
#pragma unroll
      for (int q = 0; q < 4; q++){ p[q] = acc0[q]; p[4+q] = acc1[q]; }
    }
    __syncthreads();
    if (kc == 0){
#pragma unroll
      for (int s = 0; s < 3; s++){
        const float* p = &red[(s*4 + wsub)*64*9 + lane*9];
#pragma unroll
        for (int q = 0; q < 4; q++){ acc0[q] += p[q]; acc1[q] += p[4+q]; }
      }
#pragma unroll
      for (int q = 0; q < 4; q++){
        const int brow = rbase + q;
        float s0 = sigmoidf_(acc0[q] + b0);
        float s1 = sigmoidf_(acc1[q] + b1);
        samples[(size_t)brow*TT*CC + (size_t)t*CC + caB] = s0;
        samples[(size_t)brow*TT*CC + (size_t)t*CC + cbB] = s1;
        st_sys_bf16(cout + (size_t)brow*CC + caB, s0);
        st_sys_bf16(cout + (size_t)brow*CC + cbB, s1);
      }
    }
  };

  // ---------------- phase A: GRU cell -> h_t -------------------------------
  auto phaseA = [&](const __hip_bfloat16* codes, const __hip_bfloat16* hprev,
                    __hip_bfloat16* hnext, int t, bool first){
    const __hip_bfloat16* arow = codes + (size_t)(m0+rl)*CC + kc*512 + kg*8;
    const __hip_bfloat16* wr   = wih   + (size_t)jA*CC + kc*512 + kg*8;
    const __hip_bfloat16* wz   = wr + (size_t)HD*CC;
    const __hip_bfloat16* wn   = wz + (size_t)HD*CC;
    f32x4 zz4 = {0.f,0.f,0.f,0.f};
    f32x4 a0=zz4, a1=zz4, a2=zz4, a3=zz4, a4=zz4, a5=zz4;
#pragma unroll 4
    for (int k = 0; k < 512; k += 32){
      bf16x8 a  = ldfrag_sys(arow + k);
      bf16x8 fr = ldfrag(wr + k);
      bf16x8 fz = ldfrag(wz + k);
      bf16x8 fn = ldfrag(wn + k);
      a0 = MFMA(a, fr, a0);
      a1 = MFMA(a, fz, a1);
      a2 = MFMA(a, fn, a2);
    }
    if (!first){
      const __hip_bfloat16* hrow = hprev + (size_t)(m0+rl)*HD + kc*256 + kg*8;
      const __hip_bfloat16* vr   = whh   + (size_t)jA*HD + kc*256 + kg*8;
      const __hip_bfloat16* vz   = vr + (size_t)HD*HD;
      const __hip_bfloat16* vn   = vz + (size_t)HD*HD;
#pragma unroll 4
      for (int k = 0; k < 256; k += 32){
        bf16x8 a  = ldfrag_sys(hrow + k);
        bf16x8 fr = ldfrag(vr + k);
        bf16x8 fz = ldfrag(vz + k);
        bf16x8 fn = ldfrag(vn + k);
        a3 = MFMA(a, fr, a3);
        a4 = MFMA(a, fz, a4);
        a5 = MFMA(a, fn, a5);
      }
    }
    // two-stage K-chunk reduction through LDS
    if (kc >= 2){
      float* p = &red[((kc-2)*4 + wsub)*64*25 + lane*25];
#pragma unroll
      for (int q = 0; q < 4; q++){
        p[q] = a0[q]; p[4+q] = a1[q]; p[8+q] = a2[q];
        p[12+q] = a3[q]; p[16+q] = a4[q]; p[20+q] = a5[q];
      }
    }
    __syncthreads();
    if (kc < 2){
      const float* p = &red[(kc*4 + wsub)*64*25 + lane*25];
#pragma unroll
      for (int q = 0; q < 4; q++){
        a0[q] += p[q]; a1[q] += p[4+q]; a2[q] += p[8+q];
        a3[q] += p[12+q]; a4[q] += p[16+q]; a5[q] += p[20+q];
      }
    }
    __syncthreads();
    if (kc == 1){
      float* p = &red[wsub*64*25 + lane*25];
#pragma unroll
      for (int q = 0; q < 4; q++){
        p[q] = a0[q]; p[4+q] = a1[q]; p[8+q] = a2[q];
        p[12+q] = a3[q]; p[16+q] = a4[q]; p[20+q] = a5[q];
      }
    }
    __syncthreads();
    if (kc == 0){
      const float* p = &red[wsub*64*25 + lane*25];
#pragma unroll
      for (int q = 0; q < 4; q++){
        a0[q] += p[q]; a1[q] += p[4+q]; a2[q] += p[8+q];
        a3[q] += p[12+q]; a4[q] += p[16+q]; a5[q] += p[20+q];
      }
#pragma unroll
      for (int q = 0; q < 4; q++){
        const int brow = rbase + q;
        float ir = a0[q] + bir, iz = a1[q] + biz, inn = a2[q] + bin;
        float hr = a3[q] + bhr, hz = a4[q] + bhz, hn = a5[q] + bhn;
        float r = sigmoidf_(ir + hr);
        float z = sigmoidf_(iz + hz);
        float n = tanhf_(inn + r*hn);
        float hp = first ? 0.0f : ld_sys_bf16(hprev + (size_t)brow*HD + jA);
        float hv = (1.0f - z)*n + z*hp;
        hiddens[(size_t)brow*TT*HD + (size_t)t*HD + jA] = hv;
        st_sys_bf16(hnext + (size_t)brow*HD + jA, hv);
      }
    }
  };

  // ---------------- sequence ----------------
  phaseB(noise16, 0, false);           // samples[:,0,:], codes_0 -> codesA
  signal(flagB, 1u);

#pragma unroll 1
  for (int t = 0; t < TT; t++){
    const __hip_bfloat16* ccur  = (t & 1) ? codesB : codesA;   // codes_t
    const __hip_bfloat16* hprev = (t & 1) ? hA : hB;           // h_{t-1}
    __hip_bfloat16* hnext       = (t & 1) ? hB : hA;           // h_t
    waitf(flagB, (unsigned)(t+1));
    phaseA(ccur, hprev, hnext, t, t == 0);
    signal(flagA, (unsigned)(t+1));
    if (t < TT-1){
      waitf(flagA, (unsigned)(t+1));
      phaseB(hnext, t+1, true);        // codes_{t+1}
      signal(flagB, (unsigned)(t+2));
    }
  }
}

extern "C" void kernel_launch(void* const* d_in, const int* in_sizes, int n_in,
                              void* d_out, int out_size, void* d_ws, size_t ws_size,
                              hipStream_t stream) {
  const float* noise = (const float*)d_in[0];
  const float* W_ih  = (const float*)d_in[1];
  const float* b_ih  = (const float*)d_in[2];
  const float* W_hh  = (const float*)d_in[3];
  const float* b_hh  = (const float*)d_in[4];
  const float* W_out = (const float*)d_in[5];
  const float* b_out = (const float*)d_in[6];

  float* samples = (float*)d_out;                       // [B][T][C]
  float* hiddens = samples + (size_t)BB*TT*CC;          // [B][T][H]

  char* w = (char*)d_ws;
  unsigned* flagA = (unsigned*)w;              w += 1024;   // 256 uints
  unsigned* flagB = (unsigned*)w;              w += 1024;
  __hip_bfloat16* wih16 = (__hip_bfloat16*)w;  w += (size_t)H3*CC*2;
  __hip_bfloat16* whh16 = (__hip_bfloat16*)w;  w += (size_t)H3*HD*2;
  __hip_bfloat16* wout16= (__hip_bfloat16*)w;  w += (size_t)CC*HD*2;
  __hip_bfloat16* noise16=(__hip_bfloat16*)w;  w += (size_t)BB*HD*2;
  __hip_bfloat16* codesA= (__hip_bfloat16*)w;  w += (size_t)BB*CC*2;
  __hip_bfloat16* codesB= (__hip_bfloat16*)w;  w += (size_t)BB*CC*2;
  __hip_bfloat16* hA    = (__hip_bfloat16*)w;  w += (size_t)BB*HD*2;
  __hip_bfloat16* hB    = (__hip_bfloat16*)w;  w += (size_t)BB*HD*2;

  hipMemsetAsync(flagA, 0, 2048, stream);  // zero both flag arrays
  cvt_f32_bf16<<<2048, 256, 0, stream>>>(W_ih,  wih16,  H3*CC);
  cvt_f32_bf16<<<2048, 256, 0, stream>>>(W_hh,  whh16,  H3*HD);
  cvt_f32_bf16<<<1024, 256, 0, stream>>>(W_out, wout16, CC*HD);
  cvt_f32_bf16<<<256,  256, 0, stream>>>(noise, noise16, BB*HD);

  gru_persistent<<<NBLK, 1024, 0, stream>>>(
      wih16, whh16, wout16, noise16, b_ih, b_hh, b_out,
      samples, hiddens, codesA, codesB, hA, hB, flagA, flagB);
}

// Round 5
// 3247.964 us; speedup vs baseline: 1.8922x; 1.4332x over previous
//
#include <hip/hip_runtime.h>
#include <hip/hip_bf16.h>

#define BB 256      // batch
#define CC 2048     // code_num
#define HD 1024     // hidden
#define TT 64       // max_len
#define H3 3072
#define NBLK 256
#define NGRP 8      // groups (one per XCD-congruence class set)
#define GBLK 32     // blocks per group
#define GROWS 32    // batch rows per group

typedef __attribute__((ext_vector_type(8))) short bf16x8;
typedef __attribute__((ext_vector_type(4))) float f32x4;
typedef __attribute__((ext_vector_type(4))) int   i32x4;

__device__ __forceinline__ float sigmoidf_(float x){ return 1.0f/(1.0f+__expf(-x)); }
__device__ __forceinline__ float tanhf_(float x){ float e=__expf(2.0f*x); return 1.0f - 2.0f/(e+1.0f); }
__device__ __forceinline__ bf16x8 ldfrag(const __hip_bfloat16* p){
  return *reinterpret_cast<const bf16x8*>(p);
}
__device__ __forceinline__ unsigned short bfbits(float x){
  __hip_bfloat16 b = __float2bfloat16(x);
  return *reinterpret_cast<unsigned short*>(&b);
}
__device__ __forceinline__ void st_sys_bf16(__hip_bfloat16* p, float v){
  __hip_atomic_store((unsigned short*)p, bfbits(v), __ATOMIC_RELAXED, __HIP_MEMORY_SCOPE_SYSTEM);
}
// 16B system-coherent load (L1/L2-bypass, L3-served). NOT counter-tracked by
// the compiler -- must call waitv0() before consuming results.
__device__ __forceinline__ i32x4 ld_sys16(const void* p){
  i32x4 r;
  asm volatile("global_load_dwordx4 %0, %1, off sc0 sc1"
               : "=v"(r) : "v"(p) : "memory");
  return r;
}
__device__ __forceinline__ void waitv0(){
  asm volatile("s_waitcnt vmcnt(0)" ::: "memory");
  __builtin_amdgcn_sched_barrier(0);
}

__global__ void cvt_f32_bf16(const float* __restrict__ in, __hip_bfloat16* __restrict__ out, int n){
  int i = (blockIdx.x*blockDim.x + threadIdx.x)*4;
  int stride = gridDim.x*blockDim.x*4;
  for (; i < n; i += stride){
    float4 v = *reinterpret_cast<const float4*>(in + i);
    ushort4 s;
    s.x = bfbits(v.x); s.y = bfbits(v.y); s.z = bfbits(v.z); s.w = bfbits(v.w);
    *reinterpret_cast<ushort4*>(out + i) = s;
  }
}

#define MFMA(a,b,c) __builtin_amdgcn_mfma_f32_16x16x32_bf16((a),(b),(c),0,0,0)

struct St4 { i32x4 r0, r1, r2, r3; };

// Persistent GRU. 256 blocks x 1024 threads (16 waves), 1 block/CU.
// blockIdx = g*32 + bsub: group g (8 groups x 32 batch rows), member bsub.
// Same-bsub blocks are congruent mod 8 -> same XCD -> weight slice
// (~2.9 MB/XCD) stays L2-resident (no fences anywhere; activations cross
// XCDs through L3 via sc0sc1 ops only).
// Phase A: member owns 32 H-cols (96 gate-cols): 12 waves x [16m x 16j], full K.
// Phase B: member owns 64 C-cols: 8 waves x [16m x 16j], full K=1024.
__global__ __launch_bounds__(1024, 4) void gru_persistent(
    const __hip_bfloat16* __restrict__ wih,     // [3H][C]
    const __hip_bfloat16* __restrict__ whh,     // [3H][H]
    const __hip_bfloat16* __restrict__ wout,    // [C][H]
    const __hip_bfloat16* __restrict__ noise16, // [B][H]
    const float* __restrict__ bih,
    const float* __restrict__ bhh,
    const float* __restrict__ bout,
    float* __restrict__ samples,                // [B][T][C]
    float* __restrict__ hiddens,                // [B][T][H]
    __hip_bfloat16* cA, __hip_bfloat16* cB,     // [B][C] codes ping-pong
    __hip_bfloat16* hA, __hip_bfloat16* hB,     // [B][H] h ping-pong
    unsigned* flagA, unsigned* flagB)
{
  // LDS: 64KB codes k-half + 64KB h + 24KB gate exchange = 152KB
  __shared__ __align__(16) char bufC[65536];   // [32 rows][1024 bf16], swizzled
  __shared__ __align__(16) char bufH[65536];   // [32 rows][1024 bf16], swizzled
  __shared__ float eplA[12*64*8];              // 12 waves x 64 lanes x (ih4,hh4)

  const int tid  = threadIdx.x;
  const int lane = tid & 63;
  const int wid  = tid >> 6;      // 0..15
  const int g    = blockIdx.x >> 5;
  const int bsub = blockIdx.x & 31;
  const int rl   = lane & 15;
  const int kg   = lane >> 4;

  // ---- group flag barrier (monotonic generations) ----
  auto signal = [&](unsigned* flags, unsigned gen){
    __syncthreads();   // all waves' stores drained (vmcnt0) before flag
    if (tid == 0)
      __hip_atomic_store(&flags[g*GBLK + bsub], gen, __ATOMIC_RELAXED, __HIP_MEMORY_SCOPE_SYSTEM);
  };
  auto waitf = [&](unsigned* flags, unsigned gen){
    if (tid < GBLK){
      while (__hip_atomic_load(&flags[g*GBLK + tid], __ATOMIC_RELAXED, __HIP_MEMORY_SCOPE_SYSTEM) < gen)
        __builtin_amdgcn_s_sleep(4);
    }
    __syncthreads();
  };

  // ---- staging: 64KB = 4096 x 16B chunks, 4 per thread ----
  // chunk ci: row = ci>>7 (0..31), c = ci&127; LDS swizzle: c ^= row&7.
  auto issue4 = [&](const __hip_bfloat16* src, int rowStride, int colBase)->St4{
    St4 s;
    {
      int ci = tid;        int row = ci>>7, c = ci&127;
      s.r0 = ld_sys16(src + (size_t)(g*GROWS+row)*rowStride + colBase + c*8);
    }{
      int ci = tid+1024;   int row = ci>>7, c = ci&127;
      s.r1 = ld_sys16(src + (size_t)(g*GROWS+row)*rowStride + colBase + c*8);
    }{
      int ci = tid+2048;   int row = ci>>7, c = ci&127;
      s.r2 = ld_sys16(src + (size_t)(g*GROWS+row)*rowStride + colBase + c*8);
    }{
      int ci = tid+3072;   int row = ci>>7, c = ci&127;
      s.r3 = ld_sys16(src + (size_t)(g*GROWS+row)*rowStride + colBase + c*8);
    }
    return s;
  };
  auto write4 = [&](char* buf, const St4& s){
    {
      int ci = tid;        int row = ci>>7, c = ci&127;
      *(i32x4*)(buf + row*2048 + ((c ^ (row&7))<<4)) = s.r0;
    }{
      int ci = tid+1024;   int row = ci>>7, c = ci&127;
      *(i32x4*)(buf + row*2048 + ((c ^ (row&7))<<4)) = s.r1;
    }{
      int ci = tid+2048;   int row = ci>>7, c = ci&127;
      *(i32x4*)(buf + row*2048 + ((c ^ (row&7))<<4)) = s.r2;
    }{
      int ci = tid+3072;   int row = ci>>7, c = ci&127;
      *(i32x4*)(buf + row*2048 + ((c ^ (row&7))<<4)) = s.r3;
    }
  };
  // swizzled LDS A-fragment read
  auto ldsfrag = [&](const char* buf, int row, int c)->bf16x8{
    return *(const bf16x8*)(buf + row*2048 + ((c ^ (row&7))<<4));
  };

  // ---------------- phase A: GRU cell -> h_t ----------------
  auto phaseA = [&](const __hip_bfloat16* codesCur, const __hip_bfloat16* hprev,
                    __hip_bfloat16* hnext, int t, bool first){
    St4 sh, sc0, sc1;
    if (!first) sh = issue4(hprev, HD, 0);
    sc0 = issue4(codesCur, CC, 0);
    waitv0();
    if (!first) write4(bufH, sh);
    write4(bufC, sc0);
    sc1 = issue4(codesCur, CC, 1024);   // k-half 1, lands during compute-1
    __syncthreads();

    const bool act = (wid < 12);
    f32x4 accI = {0.f,0.f,0.f,0.f};   // ih part
    f32x4 accH = {0.f,0.f,0.f,0.f};   // hh part
    int mt=0, ar=0;
    const __hip_bfloat16 *wr_ih = nullptr, *wr_hh = nullptr;
    if (act){
      mt = wid & 1;
      int u = wid >> 1, gate = u % 3, hjt = u / 3;
      ar = mt*16 + rl;
      size_t jW = (size_t)(gate*HD + bsub*32 + hjt*16 + rl);
      wr_ih = wih + jW*CC + kg*8;
      wr_hh = whh + jW*HD + kg*8;
      if (!first){
#pragma unroll 8
        for (int k = 0; k < 1024; k += 32){
          int c = (k>>3) + kg;
          accH = MFMA(ldsfrag(bufH, ar, c), ldfrag(wr_hh + k), accH);
        }
      }
#pragma unroll 8
      for (int k = 0; k < 1024; k += 32){
        int c = (k>>3) + kg;
        accI = MFMA(ldsfrag(bufC, ar, c), ldfrag(wr_ih + k), accI);
      }
    }
    __syncthreads();          // bufC k-half0 consumed by all
    waitv0();                 // sc1 arrived
    write4(bufC, sc1);
    __syncthreads();
    if (act){
#pragma unroll 8
      for (int k = 0; k < 1024; k += 32){
        int c = (k>>3) + kg;
        accI = MFMA(ldsfrag(bufC, ar, c), ldfrag(wr_ih + 1024 + k), accI);
      }
      float* p = &eplA[(wid*64 + lane)*8];
      *(f32x4*)p       = accI;
      *(f32x4*)(p + 4) = accH;
    }
    __syncthreads();

    if (wid < 4){
      const int mt2 = wid & 1, hj2 = wid >> 1;
      const int jG  = bsub*32 + hj2*16 + rl;     // H column
      // writer wid = mt + 2*(gate + 3*hj)
      const float* pR = &eplA[(((mt2 + 2*(0 + 3*hj2)))*64 + lane)*8];
      const float* pZ = &eplA[(((mt2 + 2*(1 + 3*hj2)))*64 + lane)*8];
      const float* pN = &eplA[(((mt2 + 2*(2 + 3*hj2)))*64 + lane)*8];
      const float bir = bih[jG], biz = bih[jG+HD], bin = bih[jG+2*HD];
      const float bhr = bhh[jG], bhz = bhh[jG+HD], bhn = bhh[jG+2*HD];
#pragma unroll
      for (int q = 0; q < 4; q++){
        const int lr   = mt2*16 + kg*4 + q;      // local row
        const int brow = g*GROWS + lr;
        float r = sigmoidf_(pR[q] + pR[4+q] + bir + bhr);
        float z = sigmoidf_(pZ[q] + pZ[4+q] + biz + bhz);
        float n = tanhf_(pN[q] + bin + r*(pN[4+q] + bhn));
        float hp = 0.0f;
        if (!first){
          int c = jG >> 3;
          const __hip_bfloat16* hb = (const __hip_bfloat16*)
            (bufH + lr*2048 + ((c ^ (lr&7))<<4) + (jG&7)*2);
          hp = __bfloat162float(*hb);
        }
        float hv = (1.0f - z)*n + z*hp;
        __builtin_nontemporal_store(hv, &hiddens[(size_t)brow*TT*HD + (size_t)t*HD + jG]);
        st_sys_bf16(hnext + (size_t)brow*HD + jG, hv);
      }
    }
  };

  // ---------------- phase B: codes_t = sigmoid(act @ Wout^T + b) ----------
  auto phaseB = [&](const __hip_bfloat16* actSrc, __hip_bfloat16* codesDst, int t){
    St4 sh = issue4(actSrc, HD, 0);
    waitv0();
    write4(bufH, sh);
    __syncthreads();
    if (wid < 8){
      const int mt = wid & 1, cj = wid >> 1;
      const int ar = mt*16 + rl;
      const int ca = bsub*64 + cj*16 + rl;
      const __hip_bfloat16* wrow = wout + (size_t)ca*HD + kg*8;
      f32x4 acc = {0.f,0.f,0.f,0.f};
#pragma unroll 8
      for (int k = 0; k < 1024; k += 32){
        int c = (k>>3) + kg;
        acc = MFMA(ldsfrag(bufH, ar, c), ldfrag(wrow + k), acc);
      }
      const float b0 = bout[ca];
#pragma unroll
      for (int q = 0; q < 4; q++){
        const int brow = g*GROWS + mt*16 + kg*4 + q;
        float s0 = sigmoidf_(acc[q] + b0);
        __builtin_nontemporal_store(s0, &samples[(size_t)brow*TT*CC + (size_t)t*CC + ca]);
        st_sys_bf16(codesDst + (size_t)brow*CC + ca, s0);
      }
    }
  };

  // ---------------- sequence ----------------
  phaseB(noise16, cA, 0);              // samples[:,0,:], codes_0 -> cA
  signal(flagB, 1u);

#pragma unroll 1
  for (int t = 0; t < TT; t++){
    const __hip_bfloat16* codesCur = (t & 1) ? cB : cA;   // codes_t
    const __hip_bfloat16* hprev    = (t & 1) ? hA : hB;   // h_{t-1}
    __hip_bfloat16* hnext          = (t & 1) ? hB : hA;   // h_t
    waitf(flagB, (unsigned)(t+1));
    phaseA(codesCur, hprev, hnext, t, t == 0);
    signal(flagA, (unsigned)(t+1));
    if (t < TT-1){
      waitf(flagA, (unsigned)(t+1));
      phaseB(hnext, (t & 1) ? cA : cB, t+1);              // codes_{t+1}
      signal(flagB, (unsigned)(t+2));
    }
  }
}

extern "C" void kernel_launch(void* const* d_in, const int* in_sizes, int n_in,
                              void* d_out, int out_size, void* d_ws, size_t ws_size,
                              hipStream_t stream) {
  const float* noise = (const float*)d_in[0];
  const float* W_ih  = (const float*)d_in[1];
  const float* b_ih  = (const float*)d_in[2];
  const float* W_hh  = (const float*)d_in[3];
  const float* b_hh  = (const float*)d_in[4];
  const float* W_out = (const float*)d_in[5];
  const float* b_out = (const float*)d_in[6];

  float* samples = (float*)d_out;                       // [B][T][C]
  float* hiddens = samples + (size_t)BB*TT*CC;          // [B][T][H]

  char* w = (char*)d_ws;
  unsigned* flagA = (unsigned*)w;              w += 1024;   // 256 uints
  unsigned* flagB = (unsigned*)w;              w += 1024;
  __hip_bfloat16* wih16 = (__hip_bfloat16*)w;  w += (size_t)H3*CC*2;
  __hip_bfloat16* whh16 = (__hip_bfloat16*)w;  w += (size_t)H3*HD*2;
  __hip_bfloat16* wout16= (__hip_bfloat16*)w;  w += (size_t)CC*HD*2;
  __hip_bfloat16* noise16=(__hip_bfloat16*)w;  w += (size_t)BB*HD*2;
  __hip_bfloat16* cA    = (__hip_bfloat16*)w;  w += (size_t)BB*CC*2;
  __hip_bfloat16* cB    = (__hip_bfloat16*)w;  w += (size_t)BB*CC*2;
  __hip_bfloat16* hA    = (__hip_bfloat16*)w;  w += (size_t)BB*HD*2;
  __hip_bfloat16* hB    = (__hip_bfloat16*)w;  w += (size_t)BB*HD*2;

  hipMemsetAsync(flagA, 0, 2048, stream);
  cvt_f32_bf16<<<2048, 256, 0, stream>>>(W_ih,  wih16,  H3*CC);
  cvt_f32_bf16<<<2048, 256, 0, stream>>>(W_hh,  whh16,  H3*HD);
  cvt_f32_bf16<<<1024, 256, 0, stream>>>(W_out, wout16, CC*HD);
  cvt_f32_bf16<<<256,  256, 0, stream>>>(noise, noise16, BB*HD);

  gru_persistent<<<NBLK, 1024, 0, stream>>>(
      wih16, whh16, wout16, noise16, b_ih, b_hh, b_out,
      samples, hiddens, cA, cB, hA, hB, flagA, flagB);
}